// Round 11
// baseline (467.283 us; speedup 1.0000x reference)
//
#include <hip/hip_runtime.h>
#include <hip/hip_bf16.h>
#include <math.h>
#include <float.h>

#define NC 256
#define NT 2048

typedef __attribute__((ext_vector_type(4))) float f32x4;
typedef __attribute__((ext_vector_type(8))) short short8;
typedef __attribute__((ext_vector_type(8))) unsigned short ushort8;

// ws layout (34,340,864 B total — known-good size):
//   sq   double[8*2048]        @ 0
//   A-region @ A_OFF: phase A = Xh8 u16[8][32][2048][8] (+ Xl8 same at +8MB); phase B = A float
//   E-region @ E_OFF: phase A = xT float[8*2048*256]; phase B = E float
//   nb   int[8*2048*10]        @ NB_OFF
// d_out scratch until k_epi: wsc u16 @ 0; cand u16[8*2048*16] @ u16-elem 1<<20;
//                            cand2 u16[8*2048*24] @ (1<<20)+(1<<19)
#define SQ_OFF 0
#define A_OFF  131072
#define XL_OFF 8388608   // byte offset of Xl8 within A-region
#define E_OFF  16908288
#define NB_OFF 33685504

__device__ __forceinline__ int load_nf(const int* __restrict__ nf, int b) {
    bool is64 = (nf[1] == 0) & (nf[3] == 0) & (nf[5] == 0) & (nf[7] == 0);
    return is64 ? nf[2 * b] : nf[b];
}

__device__ __forceinline__ void split_bf16(float f, unsigned short& h, unsigned short& l) {
    __hip_bfloat16 hb = __float2bfloat16(f);
    float fh = __bfloat162float(hb);
    __hip_bfloat16 lb = __float2bfloat16(f - fh);
    h = *(unsigned short*)&hb;
    l = *(unsigned short*)&lb;
}

// scalar broadcast (uniform index) without LDS round-trip
__device__ __forceinline__ float rl_f(float v, int srclane) {
    return __int_as_float(__builtin_amdgcn_readlane(__float_as_int(v), srclane));
}
__device__ __forceinline__ int rl_i(int v, int srclane) {
    return __builtin_amdgcn_readlane(v, srclane);
}
// DPP row_shr:1 — shfl_up(.,1) within each 16-lane row, pure VALU
__device__ __forceinline__ float dpp_shr1_f(float v) {
    return __int_as_float(__builtin_amdgcn_update_dpp(0, __float_as_int(v), 0x111, 0xf, 0xf, false));
}
__device__ __forceinline__ int dpp_shr1_i(int v) {
    return __builtin_amdgcn_update_dpp(0, v, 0x111, 0xf, 0xf, false);
}

// ---------------- kernel 1 (r28): sq + split planes + xT, float4 loads along t,
//      xT written straight from registers (no LDS transpose buffer). ----------------
// Xh8 elem offset for (b,c,t) = ((b*32 + c/8)*2048 + t)*8 + (c%8)   [unchanged layout]
__global__ __launch_bounds__(256) void k_sqt(const float* __restrict__ x, double* __restrict__ sq,
                                             unsigned short* __restrict__ Xh8,
                                             unsigned short* __restrict__ Xl8,
                                             float* __restrict__ xT) {
    __shared__ double part[32][33];
    int b = blockIdx.y;
    int q0 = blockIdx.x * 32;
    int tid = threadIdx.x;
    int tq = tid & 7;             // t-quad: t = q0 + tq*4 + j
    int cg = tid >> 3;            // c-octet: c = cg*8 + i
    const float* xp = x + (size_t)b * NC * NT + q0 + tq * 4;
    double a0 = 0.0, a1 = 0.0, a2 = 0.0, a3 = 0.0;
    ushort8 hv[4], lw[4];
    float xv[4][8];
    #pragma unroll
    for (int i = 0; i < 8; ++i) {
        int c = cg * 8 + i;
        float4 f4 = *(const float4*)&xp[(size_t)c * NT];
        unsigned short h, l;
        split_bf16(f4.x, h, l); hv[0][i] = h; lw[0][i] = l; xv[0][i] = f4.x;
        a0 = fma((double)f4.x, (double)f4.x, a0);
        split_bf16(f4.y, h, l); hv[1][i] = h; lw[1][i] = l; xv[1][i] = f4.y;
        a1 = fma((double)f4.y, (double)f4.y, a1);
        split_bf16(f4.z, h, l); hv[2][i] = h; lw[2][i] = l; xv[2][i] = f4.z;
        a2 = fma((double)f4.z, (double)f4.z, a2);
        split_bf16(f4.w, h, l); hv[3][i] = h; lw[3][i] = l; xv[3][i] = f4.w;
        a3 = fma((double)f4.w, (double)f4.w, a3);
    }
    #pragma unroll
    for (int j = 0; j < 4; ++j) {
        int t = q0 + tq * 4 + j;
        size_t off = (((size_t)b * 32 + cg) * NT + t) * 8;
        *(ushort8*)(Xh8 + off) = hv[j];
        *(ushort8*)(Xl8 + off) = lw[j];
        float* xtr = &xT[((size_t)b * NT + t) * NC + cg * 8];
        *(float4*)xtr       = *(float4*)&xv[j][0];
        *(float4*)(xtr + 4) = *(float4*)&xv[j][4];
    }
    part[tq * 4 + 0][cg] = a0;
    part[tq * 4 + 1][cg] = a1;
    part[tq * 4 + 2][cg] = a2;
    part[tq * 4 + 3][cg] = a3;
    __syncthreads();
    if (tid < 32) {
        double s = 0.0;
        #pragma unroll
        for (int g = 0; g < 32; ++g) s += part[tid][g];
        sq[b * NT + q0 + tid] = s;
    }
}

// ---------------- kernel 1c: pre-split weights into d_out scratch ----------------
__global__ __launch_bounds__(256) void k_wsplit(const float* __restrict__ Wc, const float* __restrict__ Wm,
                                                unsigned short* __restrict__ wsc) {
    int o = blockIdx.x;
    int tid = threadIdx.x;
    #pragma unroll
    for (int i = 0; i < 3; ++i) {
        int idx = i * 256 + tid;
        int c = idx / 3, kh = idx % 3;
        float w = Wc[(size_t)o * 768 + idx];
        if (kh == 1) w += Wm[(size_t)o * 512 + 256 + c];
        unsigned short h, l;
        split_bf16(w, h, l);
        wsc[(size_t)(kh * 256 + o) * 256 + c] = h;
        wsc[196608 + (size_t)(kh * 256 + o) * 256 + c] = l;
    }
    float wa = Wm[(size_t)o * 512 + tid];
    unsigned short h, l;
    split_bf16(wa, h, l);
    wsc[393216 + (size_t)o * 256 + tid] = h;
    wsc[458752 + (size_t)o * 256 + tid] = l;
}

// ---- kernel 4a (r31): Q held in REGISTERS (qh/ql[8], 64 VGPR) — Qh/Ql LDS deleted.
//      r10 accounting: 768 loop-invariant ds_read_b128/wave (6.1 MB LDS reads/block)
//      was the dominant recurring cost (~40-100us/CU LDS-port time + 9.4M conflict cy).
//      Inner loop now: 2 global K-loads + 3 MFMAs per cc, LDS only for Df (16.6 KB).
//      __launch_bounds__(512,4) -> 128-VGPR cap (fits ~110 live). Non-pipelined r29
//      loop structure restored (r30 overlap regressed). Candidates bit-identical.
#define DFB_S 130

__global__ __launch_bounds__(512, 4) void k_knn_a(const unsigned short* __restrict__ Xh8,
                                                  const unsigned short* __restrict__ Xl8,
                                                  const double* __restrict__ sq,
                                                  const int* __restrict__ nf,
                                                  unsigned short* __restrict__ cand,
                                                  unsigned short* __restrict__ cand2) {
    __shared__ __align__(16) float Df[2][16 * DFB_S];
    int q0 = blockIdx.x * 16;
    int b = blockIdx.y;
    int tid = threadIdx.x;
    int lane = tid & 63, wave = tid >> 6;     // wave 0..7
    const unsigned short* Xh8b = Xh8 + (size_t)b * 32 * NT * 8;
    const unsigned short* Xl8b = Xl8 + (size_t)b * 32 * NT * 8;
    const double* sqb = sq + b * NT;
    int n = load_nf(nf, b);
    int thr = n + 20;
    bool need2 = (n <= 819) && (q0 + 15 >= thr);   // block-uniform
    float lv[2], lv2[2];
    int li[2], li2[2];
    #pragma unroll
    for (int rr = 0; rr < 2; ++rr) { lv[rr] = INFINITY; li[rr] = 0; lv2[rr] = INFINITY; li2[rr] = 0; }
    int quad = lane >> 4, l15 = lane & 15;
    int n0 = wave * 16 + l15;                 // key-in-panel 0..127
    // Q fragments -> registers (same values the old Qh/Ql LDS staging produced):
    // channel block cc covers channels cc*32+quad*8 .. +7 of query row l15.
    short8 qh[8], ql[8];
    #pragma unroll
    for (int cc = 0; cc < 8; ++cc) {
        size_t qoff = (((size_t)(cc * 4 + quad)) * NT + q0 + l15) * 8;
        qh[cc] = *(const short8*)(Xh8b + qoff);
        ql[cc] = *(const short8*)(Xl8b + qoff);
    }
    float sqv[4];
    #pragma unroll
    for (int bb = 0; bb < 4; ++bb) sqv[bb] = (float)sqb[q0 + quad * 4 + bb];
    // per-lane 32-bit element offset; octet/koff parts are uniform
    int lane_elem = (quad * NT + n0) * 8;
#define LD_OCT(oct, koff, ph, pl) do { \
    int o_ = lane_elem + (oct) * 4 * NT * 8 + (koff) * 8; \
    ph = *(const short8*)(Xh8b + o_); \
    pl = *(const short8*)(Xl8b + o_); \
  } while (0)
    short8 hA[2], lA[2];
    LD_OCT(0, 0, hA[0], lA[0]);
    LD_OCT(1, 0, hA[1], lA[1]);
    for (int k0 = 0; k0 < NT; k0 += 128) {
        int knext = (k0 + 128 < NT) ? (k0 + 128) : k0;   // tail: redundant reload, never consumed
        f32x4 acc0 = {0.f, 0.f, 0.f, 0.f};
        float sk0 = (float)sqb[k0 + n0];
        #pragma unroll
        for (int cc = 0; cc < 8; ++cc) {
            const int bi = cc & 1;            // compile-time under full unroll
            short8 bh = hA[bi], bl = lA[bi];
            if (cc < 6) { LD_OCT(cc + 2, k0, hA[bi], lA[bi]); }
            else        { LD_OCT(cc - 6, knext, hA[bi], lA[bi]); }
            acc0 = __builtin_amdgcn_mfma_f32_16x16x32_bf16(ql[cc], bh, acc0, 0, 0, 0);
            acc0 = __builtin_amdgcn_mfma_f32_16x16x32_bf16(qh[cc], bl, acc0, 0, 0, 0);
            acc0 = __builtin_amdgcn_mfma_f32_16x16x32_bf16(qh[cc], bh, acc0, 0, 0, 0);
        }
        int p = (k0 >> 7) & 1;
        float* DfP = Df[p];
        #pragma unroll
        for (int bb = 0; bb < 4; ++bb) {
            int mr = quad * 4 + bb;
            DfP[mr * DFB_S + n0] = sqv[bb] + sk0 - 2.f * acc0[bb];
        }
        __syncthreads();                      // single barrier per k0 (ping-pong)
        #pragma unroll
        for (int rr = 0; rr < 2; ++rr) {
            int row = wave * 2 + rr;
            #pragma unroll
            for (int g = 0; g < 2; ++g) {
                float d = DfP[row * DFB_S + g * 64 + lane];
                int kbase = k0 + g * 64;
                // list 1: unrestricted top-16 (lanes >=16 hold +INF -> self-excluded)
                // invariant: every bit in mask satisfies d < current 16th (re-filtered)
                {
                    float thr16 = rl_f(lv[rr], 15);
                    unsigned long long mask = __ballot(d < thr16);
                    while (mask) {
                        int bit = __ffsll(mask) - 1;
                        mask &= mask - 1;
                        float vv = rl_f(d, bit);
                        int jj = kbase + bit;
                        unsigned long long le = __ballot(lv[rr] <= vv);
                        int pos = __popcll(le);
                        float pv = dpp_shr1_f(lv[rr]);
                        int pj = dpp_shr1_i(li[rr]);
                        if (lane < 16) {
                            if (lane == pos)      { lv[rr] = vv; li[rr] = jj; }
                            else if (lane > pos)  { lv[rr] = pv; li[rr] = pj; }
                        }
                        mask &= __ballot(d < rl_f(lv[rr], 15));
                    }
                }
                // list 2: restricted top-24 (keys j < thr), short-batch blocks only
                bool do2 = need2 && (kbase < thr);   // wave-uniform
                if (do2) {
                    unsigned long long vmask = __ballot((kbase + lane) < thr);
                    float thr24 = rl_f(lv2[rr], 23);
                    unsigned long long mask = __ballot(d < thr24) & vmask;
                    while (mask) {
                        int bit = __ffsll(mask) - 1;
                        mask &= mask - 1;
                        float vv = rl_f(d, bit);
                        int jj = kbase + bit;
                        unsigned long long le = __ballot(lv2[rr] <= vv);
                        int pos = __popcll(le);
                        float pv = dpp_shr1_f(lv2[rr]);
                        int pj = dpp_shr1_i(li2[rr]);
                        if (lane == 16) { pv = rl_f(lv2[rr], 15); pj = rl_i(li2[rr], 15); }  // row boundary
                        if (lane < 24) {
                            if (lane == pos)      { lv2[rr] = vv; li2[rr] = jj; }
                            else if (lane > pos)  { lv2[rr] = pv; li2[rr] = pj; }
                        }
                        mask &= __ballot(d < rl_f(lv2[rr], 23));
                    }
                }
            }
        }
    }
#undef LD_OCT
    if (lane < 16) {
        #pragma unroll
        for (int rr = 0; rr < 2; ++rr)
            cand[((size_t)b * NT + q0 + wave * 2 + rr) * 16 + lane] = (unsigned short)li[rr];
    }
    if (need2 && lane < 24) {
        #pragma unroll
        for (int rr = 0; rr < 2; ++rr) {
            unsigned short v = (lv2[rr] == INFINITY) ? 0xFFFFu : (unsigned short)li2[rr];
            cand2[((size_t)b * NT + q0 + wave * 2 + rr) * 24 + lane] = v;
        }
    }
}

// ---- kernel 4a2+4b2 fused (r29): exact fp64 re-rank of list-1 (16) and, for
//      short-batch rows t >= thr, list-2 (24) with exclusion of list-1's top-5.
__global__ __launch_bounds__(256) void k_rr(const float* __restrict__ xT, const double* __restrict__ sq,
                                            const int* __restrict__ nf,
                                            const unsigned short* __restrict__ cand,
                                            const unsigned short* __restrict__ cand2,
                                            int* __restrict__ nb) {
    int b = blockIdx.y;
    int wave = threadIdx.x >> 6, lane = threadIdx.x & 63;
    int t = blockIdx.x * 4 + wave;
    int n = load_nf(nf, b);
    int thr = n + 20;
    bool rr2row = (n <= 819) && (t >= thr);       // wave-uniform
    const float* qp = &xT[((size_t)b * NT + t) * NC];
    float4 q4 = *(const float4*)&qp[lane * 4];
    double sqt = sq[b * NT + t];
    int* nrow = &nb[((size_t)b * NT + t) * 10];
    // ---- list-1 re-rank (16 candidates) ----
    const unsigned short* cr = &cand[((size_t)b * NT + t) * 16];
    double myd = 0.0; int myc = 0;
    for (int i = 0; i < 16; ++i) {
        int t2 = cr[i];
        float4 k4 = *(const float4*)&xT[((size_t)b * NT + t2) * NC + lane * 4];
        double s = fma((double)q4.w, (double)k4.w,
                   fma((double)q4.z, (double)k4.z,
                   fma((double)q4.y, (double)k4.y, (double)q4.x * (double)k4.x)));
        #pragma unroll
        for (int off = 32; off; off >>= 1) s += __shfl_xor(s, off);
        double d = sqt + sq[b * NT + t2] - 2.0 * s;
        if (lane == i) { myd = d; myc = t2; }
    }
    int rank = 0;
    for (int j = 0; j < 16; ++j) {
        double dj = __shfl(myd, j);
        int cj = __shfl(myc, j);
        if (lane < 16 && j != lane)
            rank += ((dj < myd) || (dj == myd && cj < myc)) ? 1 : 0;
    }
    if (lane < 16 && rank < 5) nrow[rank] = myc;
    bool w1hi = (lane < 16) && (rank >= 5) && (rank < 10);
    if (!rr2row) {
        if (w1hi) nrow[rank] = myc;
        return;
    }
    // capture f[0:5] = list-1 winners ranks 0..4
    int f[5];
    #pragma unroll
    for (int s = 0; s < 5; ++s) {
        unsigned long long m = __ballot((lane < 16) && (rank == s));
        f[s] = __shfl(myc, __ffsll(m) - 1);
    }
    // ---- list-2 re-rank (24 candidates, exclusion of f[0:5]) ----
    const unsigned short* cr2 = &cand2[((size_t)b * NT + t) * 24];
    double myd2 = DBL_MAX; int myc2 = 0x7FFFFFFF;
    for (int i = 0; i < 24; ++i) {
        int c16 = cr2[i];
        if (c16 == 0xFFFF) continue;
        int t2 = c16;
        float4 k4 = *(const float4*)&xT[((size_t)b * NT + t2) * NC + lane * 4];
        double s = fma((double)q4.w, (double)k4.w,
                   fma((double)q4.z, (double)k4.z,
                   fma((double)q4.y, (double)k4.y, (double)q4.x * (double)k4.x)));
        #pragma unroll
        for (int off = 32; off; off >>= 1) s += __shfl_xor(s, off);
        double d = sqt + sq[b * NT + t2] - 2.0 * s;
        if (lane == i) { myd2 = d; myc2 = t2; }
    }
    bool keep = (lane < 24) && (myc2 != 0x7FFFFFFF);
    #pragma unroll
    for (int s = 0; s < 5; ++s) keep = keep && (myc2 != f[s]);
    int rank2 = 0;
    for (int j = 0; j < 24; ++j) {
        double dj = __shfl(myd2, j);
        int cj = __shfl(myc2, j);
        bool kj = __shfl((int)keep, j);
        if (keep && kj && j != lane)
            rank2 += ((dj < myd2) || (dj == myd2 && cj < myc2)) ? 1 : 0;
    }
    int nK = __popcll(__ballot(keep)); if (nK > 5) nK = 5;
    if (keep && rank2 < 5) nrow[5 + rank2] = myc2;
    if (w1hi && (rank - 5) >= nK) nrow[rank] = myc;   // slots list-2 didn't fill
}

// ---- kernel 2 (MFMA, fused): E = conv1d (3 shifted GEMMs) + biases; A = x^T W1^T (4th tap) ----
#define XT_S 40

__global__ __launch_bounds__(256) void k_conv(const float* __restrict__ x, const unsigned short* __restrict__ wsc,
                                              const float* __restrict__ bc, const float* __restrict__ bm,
                                              float* __restrict__ E, float* __restrict__ A) {
    __shared__ __align__(16) unsigned short XTh[66 * XT_S], XTl[66 * XT_S];
    __shared__ __align__(16) unsigned short Wsh[3 * 64 * XT_S], Wsl[3 * 64 * XT_S];
    __shared__ __align__(16) unsigned short Wah[64 * XT_S], Wal[64 * XT_S];
    int tx = blockIdx.x * 64, oy = blockIdx.y * 64, b = blockIdx.z;
    int tid = threadIdx.x, lane = tid & 63, wave = tid >> 6;
    int quad = lane >> 4, l15 = lane & 15;
    f32x4 accE[4] = {}, accA[4] = {};
    for (int c0 = 0; c0 < 256; c0 += 32) {
        __syncthreads();
        #pragma unroll
        for (int i = 0; i < 8; ++i) {
            int c = wave * 8 + i;
            int t = lane;
            int g = tx - 1 + t;
            float v = (g >= 0 && g < NT) ? x[((size_t)b * NC + c0 + c) * NT + g] : 0.f;
            unsigned short h, l;
            split_bf16(v, h, l);
            XTh[t * XT_S + c] = h;
            XTl[t * XT_S + c] = l;
        }
        if (tid < 64) {
            int c = tid >> 1, t = 64 + (tid & 1);
            int g = tx - 1 + t;
            float v = (g < NT) ? x[((size_t)b * NC + c0 + c) * NT + g] : 0.f;
            unsigned short h, l;
            split_bf16(v, h, l);
            XTh[t * XT_S + c] = h;
            XTl[t * XT_S + c] = l;
        }
        #pragma unroll
        for (int i = 0; i < 3; ++i) {
            int gidx = i * 256 + tid;
            int kh = gidx >> 8;
            int o  = (gidx >> 2) & 63;
            int g4 = gidx & 3;
            uint4 vh = *(const uint4*)&wsc[(size_t)(kh * 256 + oy + o) * 256 + c0 + g4 * 8];
            *(uint4*)&Wsh[(kh * 64 + o) * XT_S + g4 * 8] = vh;
            uint4 vl = *(const uint4*)&wsc[196608 + (size_t)(kh * 256 + oy + o) * 256 + c0 + g4 * 8];
            *(uint4*)&Wsl[(kh * 64 + o) * XT_S + g4 * 8] = vl;
        }
        {
            int o = tid >> 2, g4 = tid & 3;
            uint4 vh = *(const uint4*)&wsc[393216 + (size_t)(oy + o) * 256 + c0 + g4 * 8];
            *(uint4*)&Wah[o * XT_S + g4 * 8] = vh;
            uint4 vl = *(const uint4*)&wsc[458752 + (size_t)(oy + o) * 256 + c0 + g4 * 8];
            *(uint4*)&Wal[o * XT_S + g4 * 8] = vl;
        }
        __syncthreads();
        int trow = wave * 16 + l15;
        short8 a_h[3], a_l[3];
        #pragma unroll
        for (int kh = 0; kh < 3; ++kh) {
            a_h[kh] = *(const short8*)&XTh[(trow + kh) * XT_S + quad * 8];
            a_l[kh] = *(const short8*)&XTl[(trow + kh) * XT_S + quad * 8];
        }
        #pragma unroll
        for (int ns = 0; ns < 4; ++ns) {
            int orow = ns * 16 + l15;
            short8 wa_h = *(const short8*)&Wah[orow * XT_S + quad * 8];
            short8 wa_l = *(const short8*)&Wal[orow * XT_S + quad * 8];
            accA[ns] = __builtin_amdgcn_mfma_f32_16x16x32_bf16(a_l[1], wa_h, accA[ns], 0, 0, 0);
            accA[ns] = __builtin_amdgcn_mfma_f32_16x16x32_bf16(a_h[1], wa_l, accA[ns], 0, 0, 0);
            accA[ns] = __builtin_amdgcn_mfma_f32_16x16x32_bf16(a_h[1], wa_h, accA[ns], 0, 0, 0);
            #pragma unroll
            for (int kh = 0; kh < 3; ++kh) {
                short8 w_h = *(const short8*)&Wsh[(kh * 64 + orow) * XT_S + quad * 8];
                short8 w_l = *(const short8*)&Wsl[(kh * 64 + orow) * XT_S + quad * 8];
                accE[ns] = __builtin_amdgcn_mfma_f32_16x16x32_bf16(a_l[kh], w_h, accE[ns], 0, 0, 0);
                accE[ns] = __builtin_amdgcn_mfma_f32_16x16x32_bf16(a_h[kh], w_l, accE[ns], 0, 0, 0);
                accE[ns] = __builtin_amdgcn_mfma_f32_16x16x32_bf16(a_h[kh], w_h, accE[ns], 0, 0, 0);
            }
        }
    }
    #pragma unroll
    for (int ns = 0; ns < 4; ++ns) {
        int o = oy + ns * 16 + l15;
        float bias = bc[o] + bm[o];
        #pragma unroll
        for (int r = 0; r < 4; ++r) {
            int t = tx + wave * 16 + quad * 4 + r;
            E[((size_t)b * NT + t) * 256 + o] = accE[ns][r] + bias;
            A[((size_t)b * NT + t) * 256 + o] = accA[ns][r];
        }
    }
}

// ---------------- kernel 5 (r28): epilogue, 128 x-blocks, 8 p each ----------------
__global__ __launch_bounds__(256) void k_epi(const float* __restrict__ A, const float* __restrict__ E,
                                             const int* __restrict__ nb, float* __restrict__ out) {
    __shared__ float buf[8 * 260];
    int p0 = blockIdx.x * 8;
    int b = blockIdx.y;
    int tid = threadIdx.x;
    int o4 = tid & 63;
    int pg = tid >> 6;
    #pragma unroll
    for (int pp2 = 0; pp2 < 2; ++pp2) {
        int pp = pg * 2 + pp2;
        int p = p0 + pp;
        float vm[4] = {0.f, 0.f, 0.f, 0.f};
        #pragma unroll
        for (int tt = 0; tt < 2; ++tt) {
            int t = p * 2 + tt;
            const int* nrow = &nb[((size_t)b * NT + t) * 10];
            float gm[4] = {-FLT_MAX, -FLT_MAX, -FLT_MAX, -FLT_MAX};
            #pragma unroll
            for (int k = 0; k < 10; ++k) {
                int t2 = nrow[k] & (NT - 1);
                float4 a = *(const float4*)&A[((size_t)b * NT + t2) * 256 + o4 * 4];
                gm[0] = fmaxf(gm[0], a.x); gm[1] = fmaxf(gm[1], a.y);
                gm[2] = fmaxf(gm[2], a.z); gm[3] = fmaxf(gm[3], a.w);
            }
            float4 e = *(const float4*)&E[((size_t)b * NT + t) * 256 + o4 * 4];
            vm[0] = fmaxf(vm[0], fmaxf(e.x + gm[0], 0.f));
            vm[1] = fmaxf(vm[1], fmaxf(e.y + gm[1], 0.f));
            vm[2] = fmaxf(vm[2], fmaxf(e.z + gm[2], 0.f));
            vm[3] = fmaxf(vm[3], fmaxf(e.w + gm[3], 0.f));
        }
        float4 v = {vm[0], vm[1], vm[2], vm[3]};
        *(float4*)&buf[pp * 260 + o4 * 4] = v;
    }
    __syncthreads();
    #pragma unroll
    for (int i = 0; i < 8; ++i) {
        int idx = tid + i * 256;           // 0..2047 = 256 oo x 8 pp
        int oo = idx >> 3, pp = idx & 7;
        out[((size_t)b * 256 + oo) * 1024 + p0 + pp] = buf[pp * 260 + oo];
    }
}

extern "C" void kernel_launch(void* const* d_in, const int* in_sizes, int n_in,
                              void* d_out, int out_size, void* d_ws, size_t ws_size,
                              hipStream_t stream) {
    const float* x  = (const float*)d_in[0];
    const int*   nf = (const int*)d_in[1];
    const float* Wc = (const float*)d_in[2];
    const float* bc = (const float*)d_in[3];
    const float* Wm = (const float*)d_in[4];
    const float* bm = (const float*)d_in[5];
    float* out = (float*)d_out;
    char* ws = (char*)d_ws;
    double* sq = (double*)(ws + SQ_OFF);
    float* A   = (float*)(ws + A_OFF);
    float* E   = (float*)(ws + E_OFF);
    int* nb    = (int*)(ws + NB_OFF);
    unsigned short* Xh8 = (unsigned short*)(ws + A_OFF);           // phase A (dead before k_conv)
    unsigned short* Xl8 = (unsigned short*)(ws + A_OFF + XL_OFF);  // phase A
    float* xT = (float*)(ws + E_OFF);                              // phase A (dead before k_conv)
    unsigned short* wsc   = (unsigned short*)d_out;                // d_out scratch (dead before k_epi)
    unsigned short* cand  = (unsigned short*)d_out + (1 << 20);
    unsigned short* cand2 = (unsigned short*)d_out + (1 << 20) + (1 << 19);

    k_sqt<<<dim3(64, 8), dim3(256), 0, stream>>>(x, sq, Xh8, Xl8, xT);
    k_wsplit<<<dim3(256), dim3(256), 0, stream>>>(Wc, Wm, wsc);
    k_knn_a<<<dim3(128, 8), dim3(512), 0, stream>>>(Xh8, Xl8, sq, nf, cand, cand2);
    k_rr<<<dim3(512, 8), dim3(256), 0, stream>>>(xT, sq, nf, cand, cand2, nb);
    k_conv<<<dim3(32, 4, 8), dim3(256), 0, stream>>>(x, wsc, bc, bm, E, A);
    k_epi<<<dim3(128, 8), dim3(256), 0, stream>>>(A, E, nb, out);
}

// Round 12
// 424.794 us; speedup vs baseline: 1.1000x; 1.1000x over previous
//
#include <hip/hip_runtime.h>
#include <hip/hip_bf16.h>
#include <math.h>
#include <float.h>

#define NC 256
#define NT 2048

typedef __attribute__((ext_vector_type(4))) float f32x4;
typedef __attribute__((ext_vector_type(8))) short short8;
typedef __attribute__((ext_vector_type(8))) unsigned short ushort8;

// ws layout (34,340,864 B total — known-good size):
//   sq   double[8*2048]        @ 0
//   A-region @ A_OFF: phase A = Xh8 u16[8][32][2048][8] (+ Xl8 same at +8MB); phase B = A float
//   E-region @ E_OFF: phase A = xT float[8*2048*256]; phase B = E float
//   nb   int[8*2048*10]        @ NB_OFF
// d_out scratch until k_epi: wsc u16 @ 0; cand u16[8*2048*16] @ u16-elem 1<<20;
//                            cand2 u16[8*2048*24] @ (1<<20)+(1<<19)
#define SQ_OFF 0
#define A_OFF  131072
#define XL_OFF 8388608   // byte offset of Xl8 within A-region
#define E_OFF  16908288
#define NB_OFF 33685504

__device__ __forceinline__ int load_nf(const int* __restrict__ nf, int b) {
    bool is64 = (nf[1] == 0) & (nf[3] == 0) & (nf[5] == 0) & (nf[7] == 0);
    return is64 ? nf[2 * b] : nf[b];
}

__device__ __forceinline__ void split_bf16(float f, unsigned short& h, unsigned short& l) {
    __hip_bfloat16 hb = __float2bfloat16(f);
    float fh = __bfloat162float(hb);
    __hip_bfloat16 lb = __float2bfloat16(f - fh);
    h = *(unsigned short*)&hb;
    l = *(unsigned short*)&lb;
}

// scalar broadcast (uniform index) without LDS round-trip
__device__ __forceinline__ float rl_f(float v, int srclane) {
    return __int_as_float(__builtin_amdgcn_readlane(__float_as_int(v), srclane));
}
__device__ __forceinline__ int rl_i(int v, int srclane) {
    return __builtin_amdgcn_readlane(v, srclane);
}
// DPP row_shr:1 — shfl_up(.,1) within each 16-lane row, pure VALU
__device__ __forceinline__ float dpp_shr1_f(float v) {
    return __int_as_float(__builtin_amdgcn_update_dpp(0, __float_as_int(v), 0x111, 0xf, 0xf, false));
}
__device__ __forceinline__ int dpp_shr1_i(int v) {
    return __builtin_amdgcn_update_dpp(0, v, 0x111, 0xf, 0xf, false);
}

// ---------------- kernel 1 (r28): sq + split planes + xT, float4 loads along t,
//      xT written straight from registers (no LDS transpose buffer). ----------------
// Xh8 elem offset for (b,c,t) = ((b*32 + c/8)*2048 + t)*8 + (c%8)   [unchanged layout]
__global__ __launch_bounds__(256) void k_sqt(const float* __restrict__ x, double* __restrict__ sq,
                                             unsigned short* __restrict__ Xh8,
                                             unsigned short* __restrict__ Xl8,
                                             float* __restrict__ xT) {
    __shared__ double part[32][33];
    int b = blockIdx.y;
    int q0 = blockIdx.x * 32;
    int tid = threadIdx.x;
    int tq = tid & 7;             // t-quad: t = q0 + tq*4 + j
    int cg = tid >> 3;            // c-octet: c = cg*8 + i
    const float* xp = x + (size_t)b * NC * NT + q0 + tq * 4;
    double a0 = 0.0, a1 = 0.0, a2 = 0.0, a3 = 0.0;
    ushort8 hv[4], lw[4];
    float xv[4][8];
    #pragma unroll
    for (int i = 0; i < 8; ++i) {
        int c = cg * 8 + i;
        float4 f4 = *(const float4*)&xp[(size_t)c * NT];
        unsigned short h, l;
        split_bf16(f4.x, h, l); hv[0][i] = h; lw[0][i] = l; xv[0][i] = f4.x;
        a0 = fma((double)f4.x, (double)f4.x, a0);
        split_bf16(f4.y, h, l); hv[1][i] = h; lw[1][i] = l; xv[1][i] = f4.y;
        a1 = fma((double)f4.y, (double)f4.y, a1);
        split_bf16(f4.z, h, l); hv[2][i] = h; lw[2][i] = l; xv[2][i] = f4.z;
        a2 = fma((double)f4.z, (double)f4.z, a2);
        split_bf16(f4.w, h, l); hv[3][i] = h; lw[3][i] = l; xv[3][i] = f4.w;
        a3 = fma((double)f4.w, (double)f4.w, a3);
    }
    #pragma unroll
    for (int j = 0; j < 4; ++j) {
        int t = q0 + tq * 4 + j;
        size_t off = (((size_t)b * 32 + cg) * NT + t) * 8;
        *(ushort8*)(Xh8 + off) = hv[j];
        *(ushort8*)(Xl8 + off) = lw[j];
        float* xtr = &xT[((size_t)b * NT + t) * NC + cg * 8];
        *(float4*)xtr       = *(float4*)&xv[j][0];
        *(float4*)(xtr + 4) = *(float4*)&xv[j][4];
    }
    part[tq * 4 + 0][cg] = a0;
    part[tq * 4 + 1][cg] = a1;
    part[tq * 4 + 2][cg] = a2;
    part[tq * 4 + 3][cg] = a3;
    __syncthreads();
    if (tid < 32) {
        double s = 0.0;
        #pragma unroll
        for (int g = 0; g < 32; ++g) s += part[tid][g];
        sq[b * NT + q0 + tid] = s;
    }
}

// ---------------- kernel 1c: pre-split weights into d_out scratch ----------------
__global__ __launch_bounds__(256) void k_wsplit(const float* __restrict__ Wc, const float* __restrict__ Wm,
                                                unsigned short* __restrict__ wsc) {
    int o = blockIdx.x;
    int tid = threadIdx.x;
    #pragma unroll
    for (int i = 0; i < 3; ++i) {
        int idx = i * 256 + tid;
        int c = idx / 3, kh = idx % 3;
        float w = Wc[(size_t)o * 768 + idx];
        if (kh == 1) w += Wm[(size_t)o * 512 + 256 + c];
        unsigned short h, l;
        split_bf16(w, h, l);
        wsc[(size_t)(kh * 256 + o) * 256 + c] = h;
        wsc[196608 + (size_t)(kh * 256 + o) * 256 + c] = l;
    }
    float wa = Wm[(size_t)o * 512 + tid];
    unsigned short h, l;
    split_bf16(wa, h, l);
    wsc[393216 + (size_t)o * 256 + tid] = h;
    wsc[458752 + (size_t)o * 256 + tid] = l;
}

// ---- kernel 4a (r32): r27 proven body (Qh/Ql LDS, LD_CHUNK, depth-2 prefetch,
//      (512,8), Df ping-pong, 1 barrier/k0 — 176us best) + load-balance swizzle.
//      Grid = exactly capacity (4 blk/CU, no backfill) -> occupancy deficit is
//      finish-time imbalance: list-2 work is concentrated in high-q0 tiles of
//      short batches, and cohort mates (delta wgid=256) shared the same q0.
//      Bijective remap t->(b,q0): u=t>>7; q0=((t>>3)&127)*16; b=(t+u)&7.
//      Cohort mates now differ in BOTH q0 (+512) and batch (+2); no batch<->XCD
//      pinning (r5 failure mode). Pure index remap — candidates bit-identical.
#define XQH_S 264
#define DFB_S 130

#define LD_CHUNK(chx, ph, pl) do { \
    size_t o_ = ((size_t)(((chx) & 7) * 4 + quad) * NT + (size_t)((((chx) >> 3) << 7) + n0)) * 8; \
    ph = *(const short8*)(Xh8b + o_); \
    pl = *(const short8*)(Xl8b + o_); \
  } while (0)

__global__ __launch_bounds__(512, 8) void k_knn_a(const unsigned short* __restrict__ Xh8,
                                                  const unsigned short* __restrict__ Xl8,
                                                  const double* __restrict__ sq,
                                                  const int* __restrict__ nf,
                                                  unsigned short* __restrict__ cand,
                                                  unsigned short* __restrict__ cand2) {
    __shared__ __align__(16) unsigned short Qh[16 * XQH_S];
    __shared__ __align__(16) unsigned short Ql[16 * XQH_S];
    __shared__ __align__(16) float Df[2][16 * DFB_S];
    int t_wg = blockIdx.x;                    // 0..1023
    int u = t_wg >> 7;
    int q0 = ((t_wg >> 3) & 127) * 16;
    int b = (t_wg + u) & 7;
    int tid = threadIdx.x;
    int lane = tid & 63, wave = tid >> 6;     // wave 0..7
    const unsigned short* Xh8b = Xh8 + (size_t)b * 32 * NT * 8;
    const unsigned short* Xl8b = Xl8 + (size_t)b * 32 * NT * 8;
    const double* sqb = sq + b * NT;
    int n = load_nf(nf, b);
    int thr = n + 20;
    bool need2 = (n <= 819) && (q0 + 15 >= thr);   // block-uniform
    float lv[2], lv2[2];
    int li[2], li2[2];
    #pragma unroll
    for (int rr = 0; rr < 2; ++rr) { lv[rr] = INFINITY; li[rr] = 0; lv2[rr] = INFINITY; li2[rr] = 0; }
    {
        int q = tid & 15, cgp = tid >> 4;     // 512 threads = 16 q x 32 cgroups
        size_t off = (((size_t)cgp) * NT + q0 + q) * 8;
        uint4 vh = *(const uint4*)(Xh8b + off);
        uint4 vl = *(const uint4*)(Xl8b + off);
        *(uint4*)&Qh[q * XQH_S + cgp * 8] = vh;
        *(uint4*)&Ql[q * XQH_S + cgp * 8] = vl;
    }
    int quad = lane >> 4, l15 = lane & 15;
    int qrow = l15;
    int n0 = wave * 16 + l15;                 // key-in-panel 0..127
    float sqv[4];
    #pragma unroll
    for (int bb = 0; bb < 4; ++bb) sqv[bb] = (float)sqb[q0 + quad * 4 + bb];
    __syncthreads();
    const int nch = (NT / 128) * 8;           // 128 chunks
    short8 hA[2], lA[2];
    LD_CHUNK(0, hA[0], lA[0]);
    LD_CHUNK(1, hA[1], lA[1]);
    int ch = 0;
    for (int k0 = 0; k0 < NT; k0 += 128) {
        f32x4 acc0 = {0.f, 0.f, 0.f, 0.f};
        float sk0 = (float)sqb[k0 + n0];
        #pragma unroll
        for (int cc = 0; cc < 8; ++cc) {
            const int bi = cc & 1;            // compile-time under full unroll
            short8 bh = hA[bi], bl = lA[bi];
            int chn = ch + 2;
            if (chn > nch - 1) chn = nch - 1; // tail: redundant reload, never consumed
            LD_CHUNK(chn, hA[bi], lA[bi]);
            int cb = cc << 5;
            short8 ah = *(const short8*)&Qh[qrow * XQH_S + cb + quad * 8];
            short8 al = *(const short8*)&Ql[qrow * XQH_S + cb + quad * 8];
            acc0 = __builtin_amdgcn_mfma_f32_16x16x32_bf16(al, bh, acc0, 0, 0, 0);
            acc0 = __builtin_amdgcn_mfma_f32_16x16x32_bf16(ah, bl, acc0, 0, 0, 0);
            acc0 = __builtin_amdgcn_mfma_f32_16x16x32_bf16(ah, bh, acc0, 0, 0, 0);
            ++ch;
        }
        int p = (k0 >> 7) & 1;
        float* DfP = Df[p];
        #pragma unroll
        for (int bb = 0; bb < 4; ++bb) {
            int mr = quad * 4 + bb;
            DfP[mr * DFB_S + n0] = sqv[bb] + sk0 - 2.f * acc0[bb];
        }
        __syncthreads();                      // single barrier per k0 (ping-pong)
        #pragma unroll
        for (int rr = 0; rr < 2; ++rr) {
            int row = wave * 2 + rr;
            #pragma unroll
            for (int g = 0; g < 2; ++g) {
                float d = DfP[row * DFB_S + g * 64 + lane];
                int kbase = k0 + g * 64;
                // list 1: unrestricted top-16 (lanes >=16 hold +INF -> self-excluded)
                // invariant: every bit in mask satisfies d < current 16th (re-filtered)
                {
                    float thr16 = rl_f(lv[rr], 15);
                    unsigned long long mask = __ballot(d < thr16);
                    while (mask) {
                        int bit = __ffsll(mask) - 1;
                        mask &= mask - 1;
                        float vv = rl_f(d, bit);
                        int jj = kbase + bit;
                        unsigned long long le = __ballot(lv[rr] <= vv);
                        int pos = __popcll(le);
                        float pv = dpp_shr1_f(lv[rr]);
                        int pj = dpp_shr1_i(li[rr]);
                        if (lane < 16) {
                            if (lane == pos)      { lv[rr] = vv; li[rr] = jj; }
                            else if (lane > pos)  { lv[rr] = pv; li[rr] = pj; }
                        }
                        mask &= __ballot(d < rl_f(lv[rr], 15));
                    }
                }
                // list 2: restricted top-24 (keys j < thr), short-batch blocks only
                bool do2 = need2 && (kbase < thr);   // wave-uniform
                if (do2) {
                    unsigned long long vmask = __ballot((kbase + lane) < thr);
                    float thr24 = rl_f(lv2[rr], 23);
                    unsigned long long mask = __ballot(d < thr24) & vmask;
                    while (mask) {
                        int bit = __ffsll(mask) - 1;
                        mask &= mask - 1;
                        float vv = rl_f(d, bit);
                        int jj = kbase + bit;
                        unsigned long long le = __ballot(lv2[rr] <= vv);
                        int pos = __popcll(le);
                        float pv = dpp_shr1_f(lv2[rr]);
                        int pj = dpp_shr1_i(li2[rr]);
                        if (lane == 16) { pv = rl_f(lv2[rr], 15); pj = rl_i(li2[rr], 15); }  // row boundary
                        if (lane < 24) {
                            if (lane == pos)      { lv2[rr] = vv; li2[rr] = jj; }
                            else if (lane > pos)  { lv2[rr] = pv; li2[rr] = pj; }
                        }
                        mask &= __ballot(d < rl_f(lv2[rr], 23));
                    }
                }
            }
        }
    }
    if (lane < 16) {
        #pragma unroll
        for (int rr = 0; rr < 2; ++rr)
            cand[((size_t)b * NT + q0 + wave * 2 + rr) * 16 + lane] = (unsigned short)li[rr];
    }
    if (need2 && lane < 24) {
        #pragma unroll
        for (int rr = 0; rr < 2; ++rr) {
            unsigned short v = (lv2[rr] == INFINITY) ? 0xFFFFu : (unsigned short)li2[rr];
            cand2[((size_t)b * NT + q0 + wave * 2 + rr) * 24 + lane] = v;
        }
    }
}

// ---- kernel 4a2+4b2 fused (r29): exact fp64 re-rank of list-1 (16) and, for
//      short-batch rows t >= thr, list-2 (24) with exclusion of list-1's top-5.
__global__ __launch_bounds__(256) void k_rr(const float* __restrict__ xT, const double* __restrict__ sq,
                                            const int* __restrict__ nf,
                                            const unsigned short* __restrict__ cand,
                                            const unsigned short* __restrict__ cand2,
                                            int* __restrict__ nb) {
    int b = blockIdx.y;
    int wave = threadIdx.x >> 6, lane = threadIdx.x & 63;
    int t = blockIdx.x * 4 + wave;
    int n = load_nf(nf, b);
    int thr = n + 20;
    bool rr2row = (n <= 819) && (t >= thr);       // wave-uniform
    const float* qp = &xT[((size_t)b * NT + t) * NC];
    float4 q4 = *(const float4*)&qp[lane * 4];
    double sqt = sq[b * NT + t];
    int* nrow = &nb[((size_t)b * NT + t) * 10];
    // ---- list-1 re-rank (16 candidates) ----
    const unsigned short* cr = &cand[((size_t)b * NT + t) * 16];
    double myd = 0.0; int myc = 0;
    for (int i = 0; i < 16; ++i) {
        int t2 = cr[i];
        float4 k4 = *(const float4*)&xT[((size_t)b * NT + t2) * NC + lane * 4];
        double s = fma((double)q4.w, (double)k4.w,
                   fma((double)q4.z, (double)k4.z,
                   fma((double)q4.y, (double)k4.y, (double)q4.x * (double)k4.x)));
        #pragma unroll
        for (int off = 32; off; off >>= 1) s += __shfl_xor(s, off);
        double d = sqt + sq[b * NT + t2] - 2.0 * s;
        if (lane == i) { myd = d; myc = t2; }
    }
    int rank = 0;
    for (int j = 0; j < 16; ++j) {
        double dj = __shfl(myd, j);
        int cj = __shfl(myc, j);
        if (lane < 16 && j != lane)
            rank += ((dj < myd) || (dj == myd && cj < myc)) ? 1 : 0;
    }
    if (lane < 16 && rank < 5) nrow[rank] = myc;
    bool w1hi = (lane < 16) && (rank >= 5) && (rank < 10);
    if (!rr2row) {
        if (w1hi) nrow[rank] = myc;
        return;
    }
    // capture f[0:5] = list-1 winners ranks 0..4
    int f[5];
    #pragma unroll
    for (int s = 0; s < 5; ++s) {
        unsigned long long m = __ballot((lane < 16) && (rank == s));
        f[s] = __shfl(myc, __ffsll(m) - 1);
    }
    // ---- list-2 re-rank (24 candidates, exclusion of f[0:5]) ----
    const unsigned short* cr2 = &cand2[((size_t)b * NT + t) * 24];
    double myd2 = DBL_MAX; int myc2 = 0x7FFFFFFF;
    for (int i = 0; i < 24; ++i) {
        int c16 = cr2[i];
        if (c16 == 0xFFFF) continue;
        int t2 = c16;
        float4 k4 = *(const float4*)&xT[((size_t)b * NT + t2) * NC + lane * 4];
        double s = fma((double)q4.w, (double)k4.w,
                   fma((double)q4.z, (double)k4.z,
                   fma((double)q4.y, (double)k4.y, (double)q4.x * (double)k4.x)));
        #pragma unroll
        for (int off = 32; off; off >>= 1) s += __shfl_xor(s, off);
        double d = sqt + sq[b * NT + t2] - 2.0 * s;
        if (lane == i) { myd2 = d; myc2 = t2; }
    }
    bool keep = (lane < 24) && (myc2 != 0x7FFFFFFF);
    #pragma unroll
    for (int s = 0; s < 5; ++s) keep = keep && (myc2 != f[s]);
    int rank2 = 0;
    for (int j = 0; j < 24; ++j) {
        double dj = __shfl(myd2, j);
        int cj = __shfl(myc2, j);
        bool kj = __shfl((int)keep, j);
        if (keep && kj && j != lane)
            rank2 += ((dj < myd2) || (dj == myd2 && cj < myc2)) ? 1 : 0;
    }
    int nK = __popcll(__ballot(keep)); if (nK > 5) nK = 5;
    if (keep && rank2 < 5) nrow[5 + rank2] = myc2;
    if (w1hi && (rank - 5) >= nK) nrow[rank] = myc;   // slots list-2 didn't fill
}

// ---- kernel 2 (MFMA, fused): E = conv1d (3 shifted GEMMs) + biases; A = x^T W1^T (4th tap) ----
#define XT_S 40

__global__ __launch_bounds__(256) void k_conv(const float* __restrict__ x, const unsigned short* __restrict__ wsc,
                                              const float* __restrict__ bc, const float* __restrict__ bm,
                                              float* __restrict__ E, float* __restrict__ A) {
    __shared__ __align__(16) unsigned short XTh[66 * XT_S], XTl[66 * XT_S];
    __shared__ __align__(16) unsigned short Wsh[3 * 64 * XT_S], Wsl[3 * 64 * XT_S];
    __shared__ __align__(16) unsigned short Wah[64 * XT_S], Wal[64 * XT_S];
    int tx = blockIdx.x * 64, oy = blockIdx.y * 64, b = blockIdx.z;
    int tid = threadIdx.x, lane = tid & 63, wave = tid >> 6;
    int quad = lane >> 4, l15 = lane & 15;
    f32x4 accE[4] = {}, accA[4] = {};
    for (int c0 = 0; c0 < 256; c0 += 32) {
        __syncthreads();
        #pragma unroll
        for (int i = 0; i < 8; ++i) {
            int c = wave * 8 + i;
            int t = lane;
            int g = tx - 1 + t;
            float v = (g >= 0 && g < NT) ? x[((size_t)b * NC + c0 + c) * NT + g] : 0.f;
            unsigned short h, l;
            split_bf16(v, h, l);
            XTh[t * XT_S + c] = h;
            XTl[t * XT_S + c] = l;
        }
        if (tid < 64) {
            int c = tid >> 1, t = 64 + (tid & 1);
            int g = tx - 1 + t;
            float v = (g < NT) ? x[((size_t)b * NC + c0 + c) * NT + g] : 0.f;
            unsigned short h, l;
            split_bf16(v, h, l);
            XTh[t * XT_S + c] = h;
            XTl[t * XT_S + c] = l;
        }
        #pragma unroll
        for (int i = 0; i < 3; ++i) {
            int gidx = i * 256 + tid;
            int kh = gidx >> 8;
            int o  = (gidx >> 2) & 63;
            int g4 = gidx & 3;
            uint4 vh = *(const uint4*)&wsc[(size_t)(kh * 256 + oy + o) * 256 + c0 + g4 * 8];
            *(uint4*)&Wsh[(kh * 64 + o) * XT_S + g4 * 8] = vh;
            uint4 vl = *(const uint4*)&wsc[196608 + (size_t)(kh * 256 + oy + o) * 256 + c0 + g4 * 8];
            *(uint4*)&Wsl[(kh * 64 + o) * XT_S + g4 * 8] = vl;
        }
        {
            int o = tid >> 2, g4 = tid & 3;
            uint4 vh = *(const uint4*)&wsc[393216 + (size_t)(oy + o) * 256 + c0 + g4 * 8];
            *(uint4*)&Wah[o * XT_S + g4 * 8] = vh;
            uint4 vl = *(const uint4*)&wsc[458752 + (size_t)(oy + o) * 256 + c0 + g4 * 8];
            *(uint4*)&Wal[o * XT_S + g4 * 8] = vl;
        }
        __syncthreads();
        int trow = wave * 16 + l15;
        short8 a_h[3], a_l[3];
        #pragma unroll
        for (int kh = 0; kh < 3; ++kh) {
            a_h[kh] = *(const short8*)&XTh[(trow + kh) * XT_S + quad * 8];
            a_l[kh] = *(const short8*)&XTl[(trow + kh) * XT_S + quad * 8];
        }
        #pragma unroll
        for (int ns = 0; ns < 4; ++ns) {
            int orow = ns * 16 + l15;
            short8 wa_h = *(const short8*)&Wah[orow * XT_S + quad * 8];
            short8 wa_l = *(const short8*)&Wal[orow * XT_S + quad * 8];
            accA[ns] = __builtin_amdgcn_mfma_f32_16x16x32_bf16(a_l[1], wa_h, accA[ns], 0, 0, 0);
            accA[ns] = __builtin_amdgcn_mfma_f32_16x16x32_bf16(a_h[1], wa_l, accA[ns], 0, 0, 0);
            accA[ns] = __builtin_amdgcn_mfma_f32_16x16x32_bf16(a_h[1], wa_h, accA[ns], 0, 0, 0);
            #pragma unroll
            for (int kh = 0; kh < 3; ++kh) {
                short8 w_h = *(const short8*)&Wsh[(kh * 64 + orow) * XT_S + quad * 8];
                short8 w_l = *(const short8*)&Wsl[(kh * 64 + orow) * XT_S + quad * 8];
                accE[ns] = __builtin_amdgcn_mfma_f32_16x16x32_bf16(a_l[kh], w_h, accE[ns], 0, 0, 0);
                accE[ns] = __builtin_amdgcn_mfma_f32_16x16x32_bf16(a_h[kh], w_l, accE[ns], 0, 0, 0);
                accE[ns] = __builtin_amdgcn_mfma_f32_16x16x32_bf16(a_h[kh], w_h, accE[ns], 0, 0, 0);
            }
        }
    }
    #pragma unroll
    for (int ns = 0; ns < 4; ++ns) {
        int o = oy + ns * 16 + l15;
        float bias = bc[o] + bm[o];
        #pragma unroll
        for (int r = 0; r < 4; ++r) {
            int t = tx + wave * 16 + quad * 4 + r;
            E[((size_t)b * NT + t) * 256 + o] = accE[ns][r] + bias;
            A[((size_t)b * NT + t) * 256 + o] = accA[ns][r];
        }
    }
}

// ---------------- kernel 5 (r28): epilogue, 128 x-blocks, 8 p each ----------------
__global__ __launch_bounds__(256) void k_epi(const float* __restrict__ A, const float* __restrict__ E,
                                             const int* __restrict__ nb, float* __restrict__ out) {
    __shared__ float buf[8 * 260];
    int p0 = blockIdx.x * 8;
    int b = blockIdx.y;
    int tid = threadIdx.x;
    int o4 = tid & 63;
    int pg = tid >> 6;
    #pragma unroll
    for (int pp2 = 0; pp2 < 2; ++pp2) {
        int pp = pg * 2 + pp2;
        int p = p0 + pp;
        float vm[4] = {0.f, 0.f, 0.f, 0.f};
        #pragma unroll
        for (int tt = 0; tt < 2; ++tt) {
            int t = p * 2 + tt;
            const int* nrow = &nb[((size_t)b * NT + t) * 10];
            float gm[4] = {-FLT_MAX, -FLT_MAX, -FLT_MAX, -FLT_MAX};
            #pragma unroll
            for (int k = 0; k < 10; ++k) {
                int t2 = nrow[k] & (NT - 1);
                float4 a = *(const float4*)&A[((size_t)b * NT + t2) * 256 + o4 * 4];
                gm[0] = fmaxf(gm[0], a.x); gm[1] = fmaxf(gm[1], a.y);
                gm[2] = fmaxf(gm[2], a.z); gm[3] = fmaxf(gm[3], a.w);
            }
            float4 e = *(const float4*)&E[((size_t)b * NT + t) * 256 + o4 * 4];
            vm[0] = fmaxf(vm[0], fmaxf(e.x + gm[0], 0.f));
            vm[1] = fmaxf(vm[1], fmaxf(e.y + gm[1], 0.f));
            vm[2] = fmaxf(vm[2], fmaxf(e.z + gm[2], 0.f));
            vm[3] = fmaxf(vm[3], fmaxf(e.w + gm[3], 0.f));
        }
        float4 v = {vm[0], vm[1], vm[2], vm[3]};
        *(float4*)&buf[pp * 260 + o4 * 4] = v;
    }
    __syncthreads();
    #pragma unroll
    for (int i = 0; i < 8; ++i) {
        int idx = tid + i * 256;           // 0..2047 = 256 oo x 8 pp
        int oo = idx >> 3, pp = idx & 7;
        out[((size_t)b * 256 + oo) * 1024 + p0 + pp] = buf[pp * 260 + oo];
    }
}

extern "C" void kernel_launch(void* const* d_in, const int* in_sizes, int n_in,
                              void* d_out, int out_size, void* d_ws, size_t ws_size,
                              hipStream_t stream) {
    const float* x  = (const float*)d_in[0];
    const int*   nf = (const int*)d_in[1];
    const float* Wc = (const float*)d_in[2];
    const float* bc = (const float*)d_in[3];
    const float* Wm = (const float*)d_in[4];
    const float* bm = (const float*)d_in[5];
    float* out = (float*)d_out;
    char* ws = (char*)d_ws;
    double* sq = (double*)(ws + SQ_OFF);
    float* A   = (float*)(ws + A_OFF);
    float* E   = (float*)(ws + E_OFF);
    int* nb    = (int*)(ws + NB_OFF);
    unsigned short* Xh8 = (unsigned short*)(ws + A_OFF);           // phase A (dead before k_conv)
    unsigned short* Xl8 = (unsigned short*)(ws + A_OFF + XL_OFF);  // phase A
    float* xT = (float*)(ws + E_OFF);                              // phase A (dead before k_conv)
    unsigned short* wsc   = (unsigned short*)d_out;                // d_out scratch (dead before k_epi)
    unsigned short* cand  = (unsigned short*)d_out + (1 << 20);
    unsigned short* cand2 = (unsigned short*)d_out + (1 << 20) + (1 << 19);

    k_sqt<<<dim3(64, 8), dim3(256), 0, stream>>>(x, sq, Xh8, Xl8, xT);
    k_wsplit<<<dim3(256), dim3(256), 0, stream>>>(Wc, Wm, wsc);
    k_knn_a<<<dim3(1024), dim3(512), 0, stream>>>(Xh8, Xl8, sq, nf, cand, cand2);
    k_rr<<<dim3(512, 8), dim3(256), 0, stream>>>(xT, sq, nf, cand, cand2, nb);
    k_conv<<<dim3(32, 4, 8), dim3(256), 0, stream>>>(x, wsc, bc, bm, E, A);
    k_epi<<<dim3(128, 8), dim3(256), 0, stream>>>(A, E, nb, out);
}

// Round 13
// 401.042 us; speedup vs baseline: 1.1652x; 1.0592x over previous
//
#include <hip/hip_runtime.h>
#include <hip/hip_bf16.h>
#include <math.h>
#include <float.h>

#define NC 256
#define NT 2048

typedef __attribute__((ext_vector_type(4))) float f32x4;
typedef __attribute__((ext_vector_type(8))) short short8;
typedef __attribute__((ext_vector_type(8))) unsigned short ushort8;

// ws layout (34,340,864 B total — known-good size):
//   sq   double[8*2048]        @ 0
//   A-region @ A_OFF: phase A = Xh8 u16[8][32][2048][8] (+ Xl8 same at +8MB); phase B = A float
//   E-region @ E_OFF: phase A = xT float[8*2048*256]; phase B = E float
//   nb   int[8*2048*10]        @ NB_OFF
// d_out scratch until k_epi: wsc u16 @ 0 (weights for k_conv)
#define SQ_OFF 0
#define A_OFF  131072
#define XL_OFF 8388608   // byte offset of Xl8 within A-region
#define E_OFF  16908288
#define NB_OFF 33685504

__device__ __forceinline__ int load_nf(const int* __restrict__ nf, int b) {
    bool is64 = (nf[1] == 0) & (nf[3] == 0) & (nf[5] == 0) & (nf[7] == 0);
    return is64 ? nf[2 * b] : nf[b];
}

__device__ __forceinline__ void split_bf16(float f, unsigned short& h, unsigned short& l) {
    __hip_bfloat16 hb = __float2bfloat16(f);
    float fh = __bfloat162float(hb);
    __hip_bfloat16 lb = __float2bfloat16(f - fh);
    h = *(unsigned short*)&hb;
    l = *(unsigned short*)&lb;
}

// scalar broadcast (uniform index) without LDS round-trip
__device__ __forceinline__ float rl_f(float v, int srclane) {
    return __int_as_float(__builtin_amdgcn_readlane(__float_as_int(v), srclane));
}
__device__ __forceinline__ int rl_i(int v, int srclane) {
    return __builtin_amdgcn_readlane(v, srclane);
}
// DPP row_shr:1 — shfl_up(.,1) within each 16-lane row, pure VALU
__device__ __forceinline__ float dpp_shr1_f(float v) {
    return __int_as_float(__builtin_amdgcn_update_dpp(0, __float_as_int(v), 0x111, 0xf, 0xf, false));
}
__device__ __forceinline__ int dpp_shr1_i(int v) {
    return __builtin_amdgcn_update_dpp(0, v, 0x111, 0xf, 0xf, false);
}

// ---------------- kernel 1 (r28): sq + split planes + xT, float4 loads along t,
//      xT written straight from registers (no LDS transpose buffer). ----------------
// Xh8 elem offset for (b,c,t) = ((b*32 + c/8)*2048 + t)*8 + (c%8)   [unchanged layout]
__global__ __launch_bounds__(256) void k_sqt(const float* __restrict__ x, double* __restrict__ sq,
                                             unsigned short* __restrict__ Xh8,
                                             unsigned short* __restrict__ Xl8,
                                             float* __restrict__ xT) {
    __shared__ double part[32][33];
    int b = blockIdx.y;
    int q0 = blockIdx.x * 32;
    int tid = threadIdx.x;
    int tq = tid & 7;             // t-quad: t = q0 + tq*4 + j
    int cg = tid >> 3;            // c-octet: c = cg*8 + i
    const float* xp = x + (size_t)b * NC * NT + q0 + tq * 4;
    double a0 = 0.0, a1 = 0.0, a2 = 0.0, a3 = 0.0;
    ushort8 hv[4], lw[4];
    float xv[4][8];
    #pragma unroll
    for (int i = 0; i < 8; ++i) {
        int c = cg * 8 + i;
        float4 f4 = *(const float4*)&xp[(size_t)c * NT];
        unsigned short h, l;
        split_bf16(f4.x, h, l); hv[0][i] = h; lw[0][i] = l; xv[0][i] = f4.x;
        a0 = fma((double)f4.x, (double)f4.x, a0);
        split_bf16(f4.y, h, l); hv[1][i] = h; lw[1][i] = l; xv[1][i] = f4.y;
        a1 = fma((double)f4.y, (double)f4.y, a1);
        split_bf16(f4.z, h, l); hv[2][i] = h; lw[2][i] = l; xv[2][i] = f4.z;
        a2 = fma((double)f4.z, (double)f4.z, a2);
        split_bf16(f4.w, h, l); hv[3][i] = h; lw[3][i] = l; xv[3][i] = f4.w;
        a3 = fma((double)f4.w, (double)f4.w, a3);
    }
    #pragma unroll
    for (int j = 0; j < 4; ++j) {
        int t = q0 + tq * 4 + j;
        size_t off = (((size_t)b * 32 + cg) * NT + t) * 8;
        *(ushort8*)(Xh8 + off) = hv[j];
        *(ushort8*)(Xl8 + off) = lw[j];
        float* xtr = &xT[((size_t)b * NT + t) * NC + cg * 8];
        *(float4*)xtr       = *(float4*)&xv[j][0];
        *(float4*)(xtr + 4) = *(float4*)&xv[j][4];
    }
    part[tq * 4 + 0][cg] = a0;
    part[tq * 4 + 1][cg] = a1;
    part[tq * 4 + 2][cg] = a2;
    part[tq * 4 + 3][cg] = a3;
    __syncthreads();
    if (tid < 32) {
        double s = 0.0;
        #pragma unroll
        for (int g = 0; g < 32; ++g) s += part[tid][g];
        sq[b * NT + q0 + tid] = s;
    }
}

// ---------------- kernel 1c: pre-split weights into d_out scratch ----------------
__global__ __launch_bounds__(256) void k_wsplit(const float* __restrict__ Wc, const float* __restrict__ Wm,
                                                unsigned short* __restrict__ wsc) {
    int o = blockIdx.x;
    int tid = threadIdx.x;
    #pragma unroll
    for (int i = 0; i < 3; ++i) {
        int idx = i * 256 + tid;
        int c = idx / 3, kh = idx % 3;
        float w = Wc[(size_t)o * 768 + idx];
        if (kh == 1) w += Wm[(size_t)o * 512 + 256 + c];
        unsigned short h, l;
        split_bf16(w, h, l);
        wsc[(size_t)(kh * 256 + o) * 256 + c] = h;
        wsc[196608 + (size_t)(kh * 256 + o) * 256 + c] = l;
    }
    float wa = Wm[(size_t)o * 512 + tid];
    unsigned short h, l;
    split_bf16(wa, h, l);
    wsc[393216 + (size_t)o * 256 + tid] = h;
    wsc[458752 + (size_t)o * 256 + tid] = l;
}

// ---- kernel 4 (r33): r27 proven scan body (176us best: Qh/Ql LDS, depth-2 prefetch,
//      (512,8), Df ping-pong, 1 barrier/k0, 2D grid) + FUSED exact fp64 re-rank
//      epilogue (was k_rr). Candidate lists are still in the wave's registers at
//      scan end — re-rank sources them via readlane (sentinel lv2==INF replaces
//      0xFFFF, same set/order), identical fp64 math and tie-breaks -> nb bit-identical.
//      Deletes: k_rr launch, cand/cand2 HBM round-trip, duplicate q-row loads.
#define XQH_S 264
#define DFB_S 130

#define LD_CHUNK(chx, ph, pl) do { \
    size_t o_ = ((size_t)(((chx) & 7) * 4 + quad) * NT + (size_t)((((chx) >> 3) << 7) + n0)) * 8; \
    ph = *(const short8*)(Xh8b + o_); \
    pl = *(const short8*)(Xl8b + o_); \
  } while (0)

__global__ __launch_bounds__(512, 8) void k_knn_a(const unsigned short* __restrict__ Xh8,
                                                  const unsigned short* __restrict__ Xl8,
                                                  const double* __restrict__ sq,
                                                  const int* __restrict__ nf,
                                                  const float* __restrict__ xT,
                                                  int* __restrict__ nb) {
    __shared__ __align__(16) unsigned short Qh[16 * XQH_S];
    __shared__ __align__(16) unsigned short Ql[16 * XQH_S];
    __shared__ __align__(16) float Df[2][16 * DFB_S];
    int q0 = blockIdx.x * 16;
    int b = blockIdx.y;
    int tid = threadIdx.x;
    int lane = tid & 63, wave = tid >> 6;     // wave 0..7
    const unsigned short* Xh8b = Xh8 + (size_t)b * 32 * NT * 8;
    const unsigned short* Xl8b = Xl8 + (size_t)b * 32 * NT * 8;
    const double* sqb = sq + b * NT;
    int n = load_nf(nf, b);
    int thr = n + 20;
    bool need2 = (n <= 819) && (q0 + 15 >= thr);   // block-uniform
    float lv[2], lv2[2];
    int li[2], li2[2];
    #pragma unroll
    for (int rr = 0; rr < 2; ++rr) { lv[rr] = INFINITY; li[rr] = 0; lv2[rr] = INFINITY; li2[rr] = 0; }
    {
        int q = tid & 15, cgp = tid >> 4;     // 512 threads = 16 q x 32 cgroups
        size_t off = (((size_t)cgp) * NT + q0 + q) * 8;
        uint4 vh = *(const uint4*)(Xh8b + off);
        uint4 vl = *(const uint4*)(Xl8b + off);
        *(uint4*)&Qh[q * XQH_S + cgp * 8] = vh;
        *(uint4*)&Ql[q * XQH_S + cgp * 8] = vl;
    }
    int quad = lane >> 4, l15 = lane & 15;
    int qrow = l15;
    int n0 = wave * 16 + l15;                 // key-in-panel 0..127
    float sqv[4];
    #pragma unroll
    for (int bb = 0; bb < 4; ++bb) sqv[bb] = (float)sqb[q0 + quad * 4 + bb];
    __syncthreads();
    const int nch = (NT / 128) * 8;           // 128 chunks
    short8 hA[2], lA[2];
    LD_CHUNK(0, hA[0], lA[0]);
    LD_CHUNK(1, hA[1], lA[1]);
    int ch = 0;
    for (int k0 = 0; k0 < NT; k0 += 128) {
        f32x4 acc0 = {0.f, 0.f, 0.f, 0.f};
        float sk0 = (float)sqb[k0 + n0];
        #pragma unroll
        for (int cc = 0; cc < 8; ++cc) {
            const int bi = cc & 1;            // compile-time under full unroll
            short8 bh = hA[bi], bl = lA[bi];
            int chn = ch + 2;
            if (chn > nch - 1) chn = nch - 1; // tail: redundant reload, never consumed
            LD_CHUNK(chn, hA[bi], lA[bi]);
            int cb = cc << 5;
            short8 ah = *(const short8*)&Qh[qrow * XQH_S + cb + quad * 8];
            short8 al = *(const short8*)&Ql[qrow * XQH_S + cb + quad * 8];
            acc0 = __builtin_amdgcn_mfma_f32_16x16x32_bf16(al, bh, acc0, 0, 0, 0);
            acc0 = __builtin_amdgcn_mfma_f32_16x16x32_bf16(ah, bl, acc0, 0, 0, 0);
            acc0 = __builtin_amdgcn_mfma_f32_16x16x32_bf16(ah, bh, acc0, 0, 0, 0);
            ++ch;
        }
        int p = (k0 >> 7) & 1;
        float* DfP = Df[p];
        #pragma unroll
        for (int bb = 0; bb < 4; ++bb) {
            int mr = quad * 4 + bb;
            DfP[mr * DFB_S + n0] = sqv[bb] + sk0 - 2.f * acc0[bb];
        }
        __syncthreads();                      // single barrier per k0 (ping-pong)
        #pragma unroll
        for (int rr = 0; rr < 2; ++rr) {
            int row = wave * 2 + rr;
            #pragma unroll
            for (int g = 0; g < 2; ++g) {
                float d = DfP[row * DFB_S + g * 64 + lane];
                int kbase = k0 + g * 64;
                // list 1: unrestricted top-16 (lanes >=16 hold +INF -> self-excluded)
                // invariant: every bit in mask satisfies d < current 16th (re-filtered)
                {
                    float thr16 = rl_f(lv[rr], 15);
                    unsigned long long mask = __ballot(d < thr16);
                    while (mask) {
                        int bit = __ffsll(mask) - 1;
                        mask &= mask - 1;
                        float vv = rl_f(d, bit);
                        int jj = kbase + bit;
                        unsigned long long le = __ballot(lv[rr] <= vv);
                        int pos = __popcll(le);
                        float pv = dpp_shr1_f(lv[rr]);
                        int pj = dpp_shr1_i(li[rr]);
                        if (lane < 16) {
                            if (lane == pos)      { lv[rr] = vv; li[rr] = jj; }
                            else if (lane > pos)  { lv[rr] = pv; li[rr] = pj; }
                        }
                        mask &= __ballot(d < rl_f(lv[rr], 15));
                    }
                }
                // list 2: restricted top-24 (keys j < thr), short-batch blocks only
                bool do2 = need2 && (kbase < thr);   // wave-uniform
                if (do2) {
                    unsigned long long vmask = __ballot((kbase + lane) < thr);
                    float thr24 = rl_f(lv2[rr], 23);
                    unsigned long long mask = __ballot(d < thr24) & vmask;
                    while (mask) {
                        int bit = __ffsll(mask) - 1;
                        mask &= mask - 1;
                        float vv = rl_f(d, bit);
                        int jj = kbase + bit;
                        unsigned long long le = __ballot(lv2[rr] <= vv);
                        int pos = __popcll(le);
                        float pv = dpp_shr1_f(lv2[rr]);
                        int pj = dpp_shr1_i(li2[rr]);
                        if (lane == 16) { pv = rl_f(lv2[rr], 15); pj = rl_i(li2[rr], 15); }  // row boundary
                        if (lane < 24) {
                            if (lane == pos)      { lv2[rr] = vv; li2[rr] = jj; }
                            else if (lane > pos)  { lv2[rr] = pv; li2[rr] = pj; }
                        }
                        mask &= __ballot(d < rl_f(lv2[rr], 23));
                    }
                }
            }
        }
    }
#undef LD_CHUNK
    // ---- fused epilogue: exact fp64 re-rank (semantics identical to old k_rr) ----
    const float* xTb = xT + (size_t)b * NT * NC;
    for (int rr = 0; rr < 2; ++rr) {
        int t = q0 + wave * 2 + rr;
        bool rr2row = (n <= 819) && (t >= thr);       // wave-uniform
        float4 q4 = *(const float4*)&xTb[(size_t)t * NC + lane * 4];
        double sqt = sqb[t];
        int* nrow = &nb[((size_t)b * NT + t) * 10];
        // list-1 re-rank (16 candidates, from registers)
        double myd = 0.0; int myc = 0;
        for (int i = 0; i < 16; ++i) {
            int t2 = rl_i(li[rr], i);
            float4 k4 = *(const float4*)&xTb[(size_t)t2 * NC + lane * 4];
            double s = fma((double)q4.w, (double)k4.w,
                       fma((double)q4.z, (double)k4.z,
                       fma((double)q4.y, (double)k4.y, (double)q4.x * (double)k4.x)));
            #pragma unroll
            for (int off = 32; off; off >>= 1) s += __shfl_xor(s, off);
            double d = sqt + sqb[t2] - 2.0 * s;
            if (lane == i) { myd = d; myc = t2; }
        }
        int rank = 0;
        for (int j = 0; j < 16; ++j) {
            double dj = __shfl(myd, j);
            int cj = __shfl(myc, j);
            if (lane < 16 && j != lane)
                rank += ((dj < myd) || (dj == myd && cj < myc)) ? 1 : 0;
        }
        if (lane < 16 && rank < 5) nrow[rank] = myc;
        bool w1hi = (lane < 16) && (rank >= 5) && (rank < 10);
        if (!rr2row) {
            if (w1hi) nrow[rank] = myc;
            continue;
        }
        // capture f[0:5] = list-1 winners ranks 0..4
        int f[5];
        #pragma unroll
        for (int s = 0; s < 5; ++s) {
            unsigned long long m = __ballot((lane < 16) && (rank == s));
            f[s] = __shfl(myc, __ffsll(m) - 1);
        }
        // list-2 re-rank (24 candidates from registers; sentinel lv2==INF == old 0xFFFF)
        double myd2 = DBL_MAX; int myc2 = 0x7FFFFFFF;
        for (int i = 0; i < 24; ++i) {
            float v2 = rl_f(lv2[rr], i);          // wave-uniform
            if (v2 == INFINITY) continue;
            int t2 = rl_i(li2[rr], i);
            float4 k4 = *(const float4*)&xTb[(size_t)t2 * NC + lane * 4];
            double s = fma((double)q4.w, (double)k4.w,
                       fma((double)q4.z, (double)k4.z,
                       fma((double)q4.y, (double)k4.y, (double)q4.x * (double)k4.x)));
            #pragma unroll
            for (int off = 32; off; off >>= 1) s += __shfl_xor(s, off);
            double d = sqt + sqb[t2] - 2.0 * s;
            if (lane == i) { myd2 = d; myc2 = t2; }
        }
        bool keep = (lane < 24) && (myc2 != 0x7FFFFFFF);
        #pragma unroll
        for (int s = 0; s < 5; ++s) keep = keep && (myc2 != f[s]);
        int rank2 = 0;
        for (int j = 0; j < 24; ++j) {
            double dj = __shfl(myd2, j);
            int cj = __shfl(myc2, j);
            bool kj = __shfl((int)keep, j);
            if (keep && kj && j != lane)
                rank2 += ((dj < myd2) || (dj == myd2 && cj < myc2)) ? 1 : 0;
        }
        int nK = __popcll(__ballot(keep)); if (nK > 5) nK = 5;
        if (keep && rank2 < 5) nrow[5 + rank2] = myc2;
        if (w1hi && (rank - 5) >= nK) nrow[rank] = myc;   // slots list-2 didn't fill
    }
}

// ---- kernel 2 (MFMA, fused): E = conv1d (3 shifted GEMMs) + biases; A = x^T W1^T (4th tap) ----
#define XT_S 40

__global__ __launch_bounds__(256) void k_conv(const float* __restrict__ x, const unsigned short* __restrict__ wsc,
                                              const float* __restrict__ bc, const float* __restrict__ bm,
                                              float* __restrict__ E, float* __restrict__ A) {
    __shared__ __align__(16) unsigned short XTh[66 * XT_S], XTl[66 * XT_S];
    __shared__ __align__(16) unsigned short Wsh[3 * 64 * XT_S], Wsl[3 * 64 * XT_S];
    __shared__ __align__(16) unsigned short Wah[64 * XT_S], Wal[64 * XT_S];
    int tx = blockIdx.x * 64, oy = blockIdx.y * 64, b = blockIdx.z;
    int tid = threadIdx.x, lane = tid & 63, wave = tid >> 6;
    int quad = lane >> 4, l15 = lane & 15;
    f32x4 accE[4] = {}, accA[4] = {};
    for (int c0 = 0; c0 < 256; c0 += 32) {
        __syncthreads();
        #pragma unroll
        for (int i = 0; i < 8; ++i) {
            int c = wave * 8 + i;
            int t = lane;
            int g = tx - 1 + t;
            float v = (g >= 0 && g < NT) ? x[((size_t)b * NC + c0 + c) * NT + g] : 0.f;
            unsigned short h, l;
            split_bf16(v, h, l);
            XTh[t * XT_S + c] = h;
            XTl[t * XT_S + c] = l;
        }
        if (tid < 64) {
            int c = tid >> 1, t = 64 + (tid & 1);
            int g = tx - 1 + t;
            float v = (g < NT) ? x[((size_t)b * NC + c0 + c) * NT + g] : 0.f;
            unsigned short h, l;
            split_bf16(v, h, l);
            XTh[t * XT_S + c] = h;
            XTl[t * XT_S + c] = l;
        }
        #pragma unroll
        for (int i = 0; i < 3; ++i) {
            int gidx = i * 256 + tid;
            int kh = gidx >> 8;
            int o  = (gidx >> 2) & 63;
            int g4 = gidx & 3;
            uint4 vh = *(const uint4*)&wsc[(size_t)(kh * 256 + oy + o) * 256 + c0 + g4 * 8];
            *(uint4*)&Wsh[(kh * 64 + o) * XT_S + g4 * 8] = vh;
            uint4 vl = *(const uint4*)&wsc[196608 + (size_t)(kh * 256 + oy + o) * 256 + c0 + g4 * 8];
            *(uint4*)&Wsl[(kh * 64 + o) * XT_S + g4 * 8] = vl;
        }
        {
            int o = tid >> 2, g4 = tid & 3;
            uint4 vh = *(const uint4*)&wsc[393216 + (size_t)(oy + o) * 256 + c0 + g4 * 8];
            *(uint4*)&Wah[o * XT_S + g4 * 8] = vh;
            uint4 vl = *(const uint4*)&wsc[458752 + (size_t)(oy + o) * 256 + c0 + g4 * 8];
            *(uint4*)&Wal[o * XT_S + g4 * 8] = vl;
        }
        __syncthreads();
        int trow = wave * 16 + l15;
        short8 a_h[3], a_l[3];
        #pragma unroll
        for (int kh = 0; kh < 3; ++kh) {
            a_h[kh] = *(const short8*)&XTh[(trow + kh) * XT_S + quad * 8];
            a_l[kh] = *(const short8*)&XTl[(trow + kh) * XT_S + quad * 8];
        }
        #pragma unroll
        for (int ns = 0; ns < 4; ++ns) {
            int orow = ns * 16 + l15;
            short8 wa_h = *(const short8*)&Wah[orow * XT_S + quad * 8];
            short8 wa_l = *(const short8*)&Wal[orow * XT_S + quad * 8];
            accA[ns] = __builtin_amdgcn_mfma_f32_16x16x32_bf16(a_l[1], wa_h, accA[ns], 0, 0, 0);
            accA[ns] = __builtin_amdgcn_mfma_f32_16x16x32_bf16(a_h[1], wa_l, accA[ns], 0, 0, 0);
            accA[ns] = __builtin_amdgcn_mfma_f32_16x16x32_bf16(a_h[1], wa_h, accA[ns], 0, 0, 0);
            #pragma unroll
            for (int kh = 0; kh < 3; ++kh) {
                short8 w_h = *(const short8*)&Wsh[(kh * 64 + orow) * XT_S + quad * 8];
                short8 w_l = *(const short8*)&Wsl[(kh * 64 + orow) * XT_S + quad * 8];
                accE[ns] = __builtin_amdgcn_mfma_f32_16x16x32_bf16(a_l[kh], w_h, accE[ns], 0, 0, 0);
                accE[ns] = __builtin_amdgcn_mfma_f32_16x16x32_bf16(a_h[kh], w_l, accE[ns], 0, 0, 0);
                accE[ns] = __builtin_amdgcn_mfma_f32_16x16x32_bf16(a_h[kh], w_h, accE[ns], 0, 0, 0);
            }
        }
    }
    #pragma unroll
    for (int ns = 0; ns < 4; ++ns) {
        int o = oy + ns * 16 + l15;
        float bias = bc[o] + bm[o];
        #pragma unroll
        for (int r = 0; r < 4; ++r) {
            int t = tx + wave * 16 + quad * 4 + r;
            E[((size_t)b * NT + t) * 256 + o] = accE[ns][r] + bias;
            A[((size_t)b * NT + t) * 256 + o] = accA[ns][r];
        }
    }
}

// ---------------- kernel 5 (r28): epilogue, 128 x-blocks, 8 p each ----------------
__global__ __launch_bounds__(256) void k_epi(const float* __restrict__ A, const float* __restrict__ E,
                                             const int* __restrict__ nb, float* __restrict__ out) {
    __shared__ float buf[8 * 260];
    int p0 = blockIdx.x * 8;
    int b = blockIdx.y;
    int tid = threadIdx.x;
    int o4 = tid & 63;
    int pg = tid >> 6;
    #pragma unroll
    for (int pp2 = 0; pp2 < 2; ++pp2) {
        int pp = pg * 2 + pp2;
        int p = p0 + pp;
        float vm[4] = {0.f, 0.f, 0.f, 0.f};
        #pragma unroll
        for (int tt = 0; tt < 2; ++tt) {
            int t = p * 2 + tt;
            const int* nrow = &nb[((size_t)b * NT + t) * 10];
            float gm[4] = {-FLT_MAX, -FLT_MAX, -FLT_MAX, -FLT_MAX};
            #pragma unroll
            for (int k = 0; k < 10; ++k) {
                int t2 = nrow[k] & (NT - 1);
                float4 a = *(const float4*)&A[((size_t)b * NT + t2) * 256 + o4 * 4];
                gm[0] = fmaxf(gm[0], a.x); gm[1] = fmaxf(gm[1], a.y);
                gm[2] = fmaxf(gm[2], a.z); gm[3] = fmaxf(gm[3], a.w);
            }
            float4 e = *(const float4*)&E[((size_t)b * NT + t) * 256 + o4 * 4];
            vm[0] = fmaxf(vm[0], fmaxf(e.x + gm[0], 0.f));
            vm[1] = fmaxf(vm[1], fmaxf(e.y + gm[1], 0.f));
            vm[2] = fmaxf(vm[2], fmaxf(e.z + gm[2], 0.f));
            vm[3] = fmaxf(vm[3], fmaxf(e.w + gm[3], 0.f));
        }
        float4 v = {vm[0], vm[1], vm[2], vm[3]};
        *(float4*)&buf[pp * 260 + o4 * 4] = v;
    }
    __syncthreads();
    #pragma unroll
    for (int i = 0; i < 8; ++i) {
        int idx = tid + i * 256;           // 0..2047 = 256 oo x 8 pp
        int oo = idx >> 3, pp = idx & 7;
        out[((size_t)b * 256 + oo) * 1024 + p0 + pp] = buf[pp * 260 + oo];
    }
}

extern "C" void kernel_launch(void* const* d_in, const int* in_sizes, int n_in,
                              void* d_out, int out_size, void* d_ws, size_t ws_size,
                              hipStream_t stream) {
    const float* x  = (const float*)d_in[0];
    const int*   nf = (const int*)d_in[1];
    const float* Wc = (const float*)d_in[2];
    const float* bc = (const float*)d_in[3];
    const float* Wm = (const float*)d_in[4];
    const float* bm = (const float*)d_in[5];
    float* out = (float*)d_out;
    char* ws = (char*)d_ws;
    double* sq = (double*)(ws + SQ_OFF);
    float* A   = (float*)(ws + A_OFF);
    float* E   = (float*)(ws + E_OFF);
    int* nb    = (int*)(ws + NB_OFF);
    unsigned short* Xh8 = (unsigned short*)(ws + A_OFF);           // phase A (dead before k_conv)
    unsigned short* Xl8 = (unsigned short*)(ws + A_OFF + XL_OFF);  // phase A
    float* xT = (float*)(ws + E_OFF);                              // phase A (dead before k_conv)
    unsigned short* wsc = (unsigned short*)d_out;                  // d_out scratch (dead before k_epi)

    k_sqt<<<dim3(64, 8), dim3(256), 0, stream>>>(x, sq, Xh8, Xl8, xT);
    k_wsplit<<<dim3(256), dim3(256), 0, stream>>>(Wc, Wm, wsc);
    k_knn_a<<<dim3(128, 8), dim3(512), 0, stream>>>(Xh8, Xl8, sq, nf, xT, nb);
    k_conv<<<dim3(32, 4, 8), dim3(256), 0, stream>>>(x, wsc, bc, bm, E, A);
    k_epi<<<dim3(128, 8), dim3(256), 0, stream>>>(A, E, nb, out);
}